// Round 14
// baseline (187.402 us; speedup 1.0000x reference)
//
#include <hip/hip_runtime.h>
#include <hip/hip_cooperative_groups.h>
#include <cmath>

namespace cg = cooperative_groups;

// DBRX router: logits = x[16384,6144] @ W[6144,16]; softmax; top-4; L1-normalize.
// Outputs flat: weights fp32[16384*16] | top_weights fp32[16384*4] | experts(as float)[16384*4]
//
// R14 = R10 (proven 89us structure, byte-for-byte) fused via cooperative launch:
//   1024 blocks (tile,slice), 256 thr, 33KB LDS -> exactly 4 blocks/CU co-resident.
//   Partial phase identical to R10: 512B-contiguous staging runs, depth-1 reg
//   prefetch, lane=token compute, W via provably-uniform s_load.
//   Then ONE grid.sync(); slice-0 block of each tile finishes its 64 tokens
//   (its own logits stay in wave-0 registers; only slices 1..3 go through ws).
//   No atomics, no fences, no zero-kernel, no second dispatch.
// Fallback (cooperative launch rejected): R10 two-kernel path, unchanged.

namespace {
constexpr int TOKENS = 16384;
constexpr int DIM    = 6144;
constexpr int NE     = 16;
constexpr int TOPK   = 4;
constexpr int T_TILE = 64;
constexpr int SUPER  = 128;                // d per super (512B per row-run)
constexpr int RS     = 130;                // LDS row stride floats (520B; reads 4w/bank)
constexpr int RPAD   = 20;
constexpr int KSL    = 4;
constexpr int NTILES = TOKENS / T_TILE;    // 256
constexpr int TOPW_OFF = TOKENS * NE;
constexpr int EXP_OFF  = TOPW_OFF + TOKENS * TOPK;
}

__device__ __forceinline__ void fma16(float xs, const float* __restrict__ wrow,
                                      float (&ac)[NE]) {
    const float4 w0 = *reinterpret_cast<const float4*>(wrow + 0);
    const float4 w1 = *reinterpret_cast<const float4*>(wrow + 4);
    const float4 w2 = *reinterpret_cast<const float4*>(wrow + 8);
    const float4 w3 = *reinterpret_cast<const float4*>(wrow + 12);
    ac[0]  = fmaf(xs, w0.x, ac[0]);  ac[1]  = fmaf(xs, w0.y, ac[1]);
    ac[2]  = fmaf(xs, w0.z, ac[2]);  ac[3]  = fmaf(xs, w0.w, ac[3]);
    ac[4]  = fmaf(xs, w1.x, ac[4]);  ac[5]  = fmaf(xs, w1.y, ac[5]);
    ac[6]  = fmaf(xs, w1.z, ac[6]);  ac[7]  = fmaf(xs, w1.w, ac[7]);
    ac[8]  = fmaf(xs, w2.x, ac[8]);  ac[9]  = fmaf(xs, w2.y, ac[9]);
    ac[10] = fmaf(xs, w2.z, ac[10]); ac[11] = fmaf(xs, w2.w, ac[11]);
    ac[12] = fmaf(xs, w3.x, ac[12]); ac[13] = fmaf(xs, w3.y, ac[13]);
    ac[14] = fmaf(xs, w3.z, ac[14]); ac[15] = fmaf(xs, w3.w, ac[15]);
}

// softmax + stable top-4 + L1-normalized stores for one token
__device__ __forceinline__ void finish_token(const float (&l)[NE], int tt,
                                             float* __restrict__ out) {
    float mx = l[0];
    #pragma unroll
    for (int e = 1; e < NE; ++e) mx = fmaxf(mx, l[e]);
    float w[NE];
    float sum = 0.f;
    #pragma unroll
    for (int e = 0; e < NE; ++e) { w[e] = expf(l[e] - mx); sum += w[e]; }
    const float inv = 1.f / sum;
    #pragma unroll
    for (int e = 0; e < NE; ++e) w[e] *= inv;

    int   idx[TOPK];
    float tw[TOPK];
    unsigned used = 0;
    #pragma unroll
    for (int k = 0; k < TOPK; ++k) {
        float best = -1.f;
        int   bi   = 0;
        #pragma unroll
        for (int e = 0; e < NE; ++e) {
            const bool avail = ((used >> e) & 1u) == 0u;
            if (avail && w[e] > best) { best = w[e]; bi = e; }
        }
        used |= (1u << bi);
        idx[k] = bi;
        tw[k]  = best;
    }
    const float s4 = tw[0] + tw[1] + tw[2] + tw[3];
    const float rinv = 1.f / s4;

    float4* o0 = reinterpret_cast<float4*>(out + (size_t)tt * NE);
    o0[0] = make_float4(w[0], w[1], w[2], w[3]);
    o0[1] = make_float4(w[4], w[5], w[6], w[7]);
    o0[2] = make_float4(w[8], w[9], w[10], w[11]);
    o0[3] = make_float4(w[12], w[13], w[14], w[15]);
    *reinterpret_cast<float4*>(out + TOPW_OFF + (size_t)tt * TOPK) =
        make_float4(tw[0] * rinv, tw[1] * rinv, tw[2] * rinv, tw[3] * rinv);
    *reinterpret_cast<float4*>(out + EXP_OFF + (size_t)tt * TOPK) =
        make_float4((float)idx[0], (float)idx[1], (float)idx[2], (float)idx[3]);
}

// ---- shared partial-phase body (R10 structure). Returns wave-0's r0 (token logits). ----
template <bool COOP>
__device__ __forceinline__ void partial_body(
    const float* __restrict__ x, const float* __restrict__ W,
    float* __restrict__ partial, float (&smem)[T_TILE * RS],
    int slice, int tile, float4 (&r0)[4], bool& have_r0)
{
    constexpr int KS = DIM / KSL;          // 1536
    constexpr int NS = KS / SUPER;         // 12

    const int tid  = threadIdx.x;
    const int lane = tid & 63;
    const int wv   = tid >> 6;
    const int wvu  = __builtin_amdgcn_readfirstlane(wv);
    const int t0 = tile * T_TILE;
    const int d0 = slice * KS;

    const int srow = wv * 2 + (lane >> 5);          // 0..7
    const int scol = (lane & 31) * 4;               // 0..124
    const float* xb = x + (size_t)(t0 + srow) * DIM + d0 + scol;

    float acc[NE];
    #pragma unroll
    for (int e = 0; e < NE; ++e) acc[e] = 0.f;

    float4 buf[8];
    #pragma unroll
    for (int i = 0; i < 8; ++i)
        buf[i] = *reinterpret_cast<const float4*>(xb + (size_t)(i * 8) * DIM);

    #pragma unroll 1
    for (int s = 0; s < NS; ++s) {
        #pragma unroll
        for (int i = 0; i < 8; ++i) {
            float* dst = &smem[(size_t)(srow + i * 8) * RS + scol];
            *reinterpret_cast<float2*>(dst)     = make_float2(buf[i].x, buf[i].y);
            *reinterpret_cast<float2*>(dst + 2) = make_float2(buf[i].z, buf[i].w);
        }
        if (s + 1 < NS) {
            const float* xn = xb + (size_t)(s + 1) * SUPER;
            #pragma unroll
            for (int i = 0; i < 8; ++i)
                buf[i] = *reinterpret_cast<const float4*>(xn + (size_t)(i * 8) * DIM);
        }
        __syncthreads();
        {
            const float* xr = &smem[(size_t)lane * RS + wvu * 32];
            const float* wp = W + (size_t)(d0 + s * SUPER + wvu * 32) * NE;
            #pragma unroll
            for (int q = 0; q < 16; ++q) {
                const float2 xq = *reinterpret_cast<const float2*>(xr + 2 * q);
                fma16(xq.x, wp + (2 * q) * NE, acc);
                fma16(xq.y, wp + (2 * q + 1) * NE, acc);
            }
        }
        __syncthreads();
    }

    // in-block reduce across the 4 waves (overlay on smem)
    #pragma unroll
    for (int q = 0; q < 4; ++q)
        *reinterpret_cast<float4*>(&smem[(size_t)(wvu * 64 + lane) * RPAD + 4 * q]) =
            make_float4(acc[4 * q], acc[4 * q + 1], acc[4 * q + 2], acc[4 * q + 3]);
    __syncthreads();

    have_r0 = false;
    if (wv == 0) {
        #pragma unroll
        for (int q = 0; q < 4; ++q)
            r0[q] = *reinterpret_cast<const float4*>(&smem[(size_t)lane * RPAD + 4 * q]);
        #pragma unroll
        for (int w = 1; w < 4; ++w) {
            #pragma unroll
            for (int q = 0; q < 4; ++q) {
                const float4 rw = *reinterpret_cast<const float4*>(
                    &smem[(size_t)(w * 64 + lane) * RPAD + 4 * q]);
                r0[q].x += rw.x; r0[q].y += rw.y; r0[q].z += rw.z; r0[q].w += rw.w;
            }
        }
        have_r0 = true;
        if (!COOP || slice != 0) {
            // COOP layout: slices 1..3 at index slice-1. Fallback: slices 0..3.
            const int sidx = COOP ? (slice - 1) : slice;
            float* p = partial + ((size_t)sidx * TOKENS + t0 * 1 + lane) * NE
                       + (size_t)tile * 0;  // (kept simple; t0 already includes tile)
            p = partial + ((size_t)sidx * TOKENS + tile * T_TILE + lane) * NE;
            #pragma unroll
            for (int q = 0; q < 4; ++q)
                *reinterpret_cast<float4*>(p + 4 * q) = r0[q];
        }
    }
}

// ---------------- cooperative fused kernel ----------------
__global__ __launch_bounds__(256, 4) void router_coop_kernel(
    const float* __restrict__ x, const float* __restrict__ W,
    float* __restrict__ partial, float* __restrict__ out)
{
    __shared__ float smem[T_TILE * RS];    // 33.3 KB
    const int slice = blockIdx.x % KSL;
    const int tile  = blockIdx.x / KSL;

    float4 r0[4];
    bool have_r0;
    partial_body<true>(x, W, partial, smem, slice, tile, r0, have_r0);

    cg::this_grid().sync();                // all partials visible grid-wide

    if (slice == 0 && have_r0) {           // wave 0 of the slice-0 block per tile
        const int lane = threadIdx.x & 63;
        const int t = tile * T_TILE + lane;
        float4 a0 = r0[0], a1 = r0[1], a2 = r0[2], a3 = r0[3];
        #pragma unroll
        for (int s = 0; s < KSL - 1; ++s) {
            const float4* q = reinterpret_cast<const float4*>(
                partial + ((size_t)s * TOKENS + t) * NE);
            float4 b0 = q[0], b1 = q[1], b2 = q[2], b3 = q[3];
            a0.x += b0.x; a0.y += b0.y; a0.z += b0.z; a0.w += b0.w;
            a1.x += b1.x; a1.y += b1.y; a1.z += b1.z; a1.w += b1.w;
            a2.x += b2.x; a2.y += b2.y; a2.z += b2.z; a2.w += b2.w;
            a3.x += b3.x; a3.y += b3.y; a3.z += b3.z; a3.w += b3.w;
        }
        float l[NE] = {a0.x,a0.y,a0.z,a0.w, a1.x,a1.y,a1.z,a1.w,
                       a2.x,a2.y,a2.z,a2.w, a3.x,a3.y,a3.z,a3.w};
        finish_token(l, t, out);
    }
}

// ---------------- fallback: R10 two-kernel path ----------------
__global__ __launch_bounds__(256) void router_partial_kernel(
    const float* __restrict__ x, const float* __restrict__ W,
    float* __restrict__ partial)
{
    __shared__ float smem[T_TILE * RS];
    const int slice = blockIdx.x % KSL;
    const int tile  = blockIdx.x / KSL;
    float4 r0[4];
    bool have_r0;
    partial_body<false>(x, W, partial, smem, slice, tile, r0, have_r0);
}

__global__ __launch_bounds__(128) void router_finish_kernel(
    const float* __restrict__ partial, float* __restrict__ out)
{
    const int t = blockIdx.x * 128 + threadIdx.x;
    float l[NE];
    {
        const float4* p0 = reinterpret_cast<const float4*>(partial + (size_t)t * NE);
        float4 a0 = p0[0], a1 = p0[1], a2 = p0[2], a3 = p0[3];
        #pragma unroll
        for (int s = 1; s < KSL; ++s) {
            const float4* q = reinterpret_cast<const float4*>(
                partial + ((size_t)s * TOKENS + t) * NE);
            float4 b0 = q[0], b1 = q[1], b2 = q[2], b3 = q[3];
            a0.x += b0.x; a0.y += b0.y; a0.z += b0.z; a0.w += b0.w;
            a1.x += b1.x; a1.y += b1.y; a1.z += b1.z; a1.w += b1.w;
            a2.x += b2.x; a2.y += b2.y; a2.z += b2.z; a2.w += b2.w;
            a3.x += b3.x; a3.y += b3.y; a3.z += b3.z; a3.w += b3.w;
        }
        l[0]=a0.x; l[1]=a0.y; l[2]=a0.z; l[3]=a0.w;
        l[4]=a1.x; l[5]=a1.y; l[6]=a1.z; l[7]=a1.w;
        l[8]=a2.x; l[9]=a2.y; l[10]=a2.z; l[11]=a2.w;
        l[12]=a3.x; l[13]=a3.y; l[14]=a3.z; l[15]=a3.w;
    }
    finish_token(l, t, out);
}

extern "C" void kernel_launch(void* const* d_in, const int* in_sizes, int n_in,
                              void* d_out, int out_size, void* d_ws, size_t ws_size,
                              hipStream_t stream) {
    const float* x = (const float*)d_in[0];
    const float* W = (const float*)d_in[1];
    float* out = (float*)d_out;
    float* ws  = (float*)d_ws;

    void* args[] = {(void*)&x, (void*)&W, (void*)&ws, (void*)&out};
    hipError_t err = hipLaunchCooperativeKernel(
        reinterpret_cast<const void*>(router_coop_kernel),
        dim3(NTILES * KSL), dim3(256), args, 0, stream);

    if (err != hipSuccess) {
        // proven R10 path
        router_partial_kernel<<<NTILES * KSL, 256, 0, stream>>>(x, W, ws);
        router_finish_kernel<<<TOKENS / 128, 128, 0, stream>>>(ws, out);
    }
}

// Round 15
// 89.433 us; speedup vs baseline: 2.0955x; 2.0955x over previous
//
#include <hip/hip_runtime.h>
#include <cmath>

// DBRX router: logits = x[16384,6144] @ W[6144,16]; softmax; top-4; L1-normalize.
// Outputs flat: weights fp32[16384*16] | top_weights fp32[16384*4] | experts(as float)[16384*4]
//
// R15 = R10 (proven 89us) + ONE change: depth-2 super prefetch (A/B reg buffers).
//   Block = 4 waves = 64 tokens x KS=1536 d (KSL=4). Super = [64 tok x 128 d].
//   STAGE: 512B contiguous per half-wave per row (rows advance 512B/super).
//   Depth-2: loads for super s+2 issued at iteration s -> ~2 full compute+barrier
//   windows of coverage; counted vmcnt keeps the younger buffer in flight.
//   COMPUTE: lane = token; wave wvu owns 32 d of the super; W via provably
//   wave-uniform s_load (blockIdx/readfirstlane-derived only).
//   NO __launch_bounds__ min-waves arg (R4/R7/R14 lesson: it starves the allocator).
// Phase 2 (finish): sum 4 partials/token, softmax, stable top-4, L1-normalize.

namespace {
constexpr int TOKENS = 16384;
constexpr int DIM    = 6144;
constexpr int NE     = 16;
constexpr int TOPK   = 4;
constexpr int T_TILE = 64;
constexpr int SUPER  = 128;                // d per super (512B per row-run)
constexpr int RS     = 130;                // LDS row stride floats (520B; b64 reads conflict-free)
constexpr int RPAD   = 20;
constexpr int TOPW_OFF = TOKENS * NE;
constexpr int EXP_OFF  = TOPW_OFF + TOKENS * TOPK;
}

__device__ __forceinline__ void fma16(float xs, const float* __restrict__ wrow,
                                      float (&ac)[NE]) {
    const float4 w0 = *reinterpret_cast<const float4*>(wrow + 0);
    const float4 w1 = *reinterpret_cast<const float4*>(wrow + 4);
    const float4 w2 = *reinterpret_cast<const float4*>(wrow + 8);
    const float4 w3 = *reinterpret_cast<const float4*>(wrow + 12);
    ac[0]  = fmaf(xs, w0.x, ac[0]);  ac[1]  = fmaf(xs, w0.y, ac[1]);
    ac[2]  = fmaf(xs, w0.z, ac[2]);  ac[3]  = fmaf(xs, w0.w, ac[3]);
    ac[4]  = fmaf(xs, w1.x, ac[4]);  ac[5]  = fmaf(xs, w1.y, ac[5]);
    ac[6]  = fmaf(xs, w1.z, ac[6]);  ac[7]  = fmaf(xs, w1.w, ac[7]);
    ac[8]  = fmaf(xs, w2.x, ac[8]);  ac[9]  = fmaf(xs, w2.y, ac[9]);
    ac[10] = fmaf(xs, w2.z, ac[10]); ac[11] = fmaf(xs, w2.w, ac[11]);
    ac[12] = fmaf(xs, w3.x, ac[12]); ac[13] = fmaf(xs, w3.y, ac[13]);
    ac[14] = fmaf(xs, w3.z, ac[14]); ac[15] = fmaf(xs, w3.w, ac[15]);
}

template <int KSL>
__global__ __launch_bounds__(256) void router_partial_kernel(
    const float* __restrict__ x, const float* __restrict__ W,
    float* __restrict__ partial)
{
    constexpr int KS = DIM / KSL;          // d per block
    constexpr int NS = KS / SUPER;         // supers per block
    static_assert(NS % 2 == 0, "A/B unroll");

    __shared__ float smem[T_TILE * RS];    // 33.3 KB (overlaid by reduce buffer)

    const int tid  = threadIdx.x;
    const int lane = tid & 63;
    const int wv   = tid >> 6;
    const int wvu  = __builtin_amdgcn_readfirstlane(wv);
    const int slice = blockIdx.x % KSL;
    const int tile  = blockIdx.x / KSL;
    const int t0 = tile * T_TILE;
    const int d0 = slice * KS;

    // stage mapping: round i (0..7): row = i*8 + wv*2 + (lane>>5); 512B run per row
    const int srow = wv * 2 + (lane >> 5);          // 0..7
    const int scol = (lane & 31) * 4;               // 0..124
    const float* xb = x + (size_t)(t0 + srow) * DIM + d0 + scol;

    float acc[NE];
    #pragma unroll
    for (int e = 0; e < NE; ++e) acc[e] = 0.f;

    float4 bufA[8], bufB[8];
    // prologue: supers 0 and 1 in flight
    #pragma unroll
    for (int i = 0; i < 8; ++i)
        bufA[i] = *reinterpret_cast<const float4*>(xb + (size_t)(i * 8) * DIM);
    #pragma unroll
    for (int i = 0; i < 8; ++i)
        bufB[i] = *reinterpret_cast<const float4*>(xb + (size_t)(i * 8) * DIM + SUPER);

    #pragma unroll 1
    for (int s = 0; s < NS; s += 2) {
        // ---- iteration s (A) ----
        #pragma unroll
        for (int i = 0; i < 8; ++i) {       // stage A (vmcnt waits A only; B stays in flight)
            float* dst = &smem[(size_t)(srow + i * 8) * RS + scol];
            *reinterpret_cast<float2*>(dst)     = make_float2(bufA[i].x, bufA[i].y);
            *reinterpret_cast<float2*>(dst + 2) = make_float2(bufA[i].z, bufA[i].w);
        }
        if (s + 2 < NS) {                   // refill A with super s+2 (2-deep coverage)
            const float* xn = xb + (size_t)(s + 2) * SUPER;
            #pragma unroll
            for (int i = 0; i < 8; ++i)
                bufA[i] = *reinterpret_cast<const float4*>(xn + (size_t)(i * 8) * DIM);
        }
        __syncthreads();
        {
            const float* xr = &smem[(size_t)lane * RS + wvu * 32];
            const float* wp = W + (size_t)(d0 + s * SUPER + wvu * 32) * NE;
            #pragma unroll
            for (int q = 0; q < 16; ++q) {
                const float2 xq = *reinterpret_cast<const float2*>(xr + 2 * q);
                fma16(xq.x, wp + (2 * q) * NE, acc);
                fma16(xq.y, wp + (2 * q + 1) * NE, acc);
            }
        }
        __syncthreads();

        // ---- iteration s+1 (B) ----
        #pragma unroll
        for (int i = 0; i < 8; ++i) {
            float* dst = &smem[(size_t)(srow + i * 8) * RS + scol];
            *reinterpret_cast<float2*>(dst)     = make_float2(bufB[i].x, bufB[i].y);
            *reinterpret_cast<float2*>(dst + 2) = make_float2(bufB[i].z, bufB[i].w);
        }
        if (s + 3 < NS) {                   // refill B with super s+3
            const float* xn = xb + (size_t)(s + 3) * SUPER;
            #pragma unroll
            for (int i = 0; i < 8; ++i)
                bufB[i] = *reinterpret_cast<const float4*>(xn + (size_t)(i * 8) * DIM);
        }
        __syncthreads();
        {
            const float* xr = &smem[(size_t)lane * RS + wvu * 32];
            const float* wp = W + (size_t)(d0 + (s + 1) * SUPER + wvu * 32) * NE;
            #pragma unroll
            for (int q = 0; q < 16; ++q) {
                const float2 xq = *reinterpret_cast<const float2*>(xr + 2 * q);
                fma16(xq.x, wp + (2 * q) * NE, acc);
                fma16(xq.y, wp + (2 * q + 1) * NE, acc);
            }
        }
        __syncthreads();
    }

    // ---- in-block reduce across the 4 waves (overlay on smem) ----
    #pragma unroll
    for (int q = 0; q < 4; ++q)
        *reinterpret_cast<float4*>(&smem[(size_t)(wvu * 64 + lane) * RPAD + 4 * q]) =
            make_float4(acc[4 * q], acc[4 * q + 1], acc[4 * q + 2], acc[4 * q + 3]);
    __syncthreads();

    if (wv == 0) {
        float4 r0[4];
        #pragma unroll
        for (int q = 0; q < 4; ++q)
            r0[q] = *reinterpret_cast<const float4*>(&smem[(size_t)lane * RPAD + 4 * q]);
        #pragma unroll
        for (int w = 1; w < 4; ++w) {
            #pragma unroll
            for (int q = 0; q < 4; ++q) {
                const float4 rw = *reinterpret_cast<const float4*>(
                    &smem[(size_t)(w * 64 + lane) * RPAD + 4 * q]);
                r0[q].x += rw.x; r0[q].y += rw.y; r0[q].z += rw.z; r0[q].w += rw.w;
            }
        }
        float* p = partial + ((size_t)slice * TOKENS + t0 + lane) * NE;
        #pragma unroll
        for (int q = 0; q < 4; ++q)
            *reinterpret_cast<float4*>(p + 4 * q) = r0[q];
    }
}

template <int KSL>
__global__ __launch_bounds__(128) void router_finish_kernel(
    const float* __restrict__ partial, float* __restrict__ out)
{
    const int t = blockIdx.x * 128 + threadIdx.x;   // one token per thread
    float l[NE];
    {
        const float4* p0 = reinterpret_cast<const float4*>(partial + (size_t)t * NE);
        float4 a0 = p0[0], a1 = p0[1], a2 = p0[2], a3 = p0[3];
        #pragma unroll
        for (int s = 1; s < KSL; ++s) {
            const float4* q = reinterpret_cast<const float4*>(
                partial + ((size_t)s * TOKENS + t) * NE);
            float4 b0 = q[0], b1 = q[1], b2 = q[2], b3 = q[3];
            a0.x += b0.x; a0.y += b0.y; a0.z += b0.z; a0.w += b0.w;
            a1.x += b1.x; a1.y += b1.y; a1.z += b1.z; a1.w += b1.w;
            a2.x += b2.x; a2.y += b2.y; a2.z += b2.z; a2.w += b2.w;
            a3.x += b3.x; a3.y += b3.y; a3.z += b3.z; a3.w += b3.w;
        }
        l[0]=a0.x; l[1]=a0.y; l[2]=a0.z; l[3]=a0.w;
        l[4]=a1.x; l[5]=a1.y; l[6]=a1.z; l[7]=a1.w;
        l[8]=a2.x; l[9]=a2.y; l[10]=a2.z; l[11]=a2.w;
        l[12]=a3.x; l[13]=a3.y; l[14]=a3.z; l[15]=a3.w;
    }
    // softmax (max-subtracted, like jax.nn.softmax)
    float mx = l[0];
    #pragma unroll
    for (int e = 1; e < NE; ++e) mx = fmaxf(mx, l[e]);
    float w[NE];
    float sum = 0.f;
    #pragma unroll
    for (int e = 0; e < NE; ++e) { w[e] = expf(l[e] - mx); sum += w[e]; }
    const float inv = 1.f / sum;
    #pragma unroll
    for (int e = 0; e < NE; ++e) w[e] *= inv;

    // stable top-4: strict '>' keeps lowest index on ties (matches jax.lax.top_k)
    int   idx[TOPK];
    float tw[TOPK];
    unsigned used = 0;
    #pragma unroll
    for (int k = 0; k < TOPK; ++k) {
        float best = -1.f;
        int   bi   = 0;
        #pragma unroll
        for (int e = 0; e < NE; ++e) {
            const bool avail = ((used >> e) & 1u) == 0u;
            if (avail && w[e] > best) { best = w[e]; bi = e; }
        }
        used |= (1u << bi);
        idx[k] = bi;
        tw[k]  = best;
    }
    const float s4 = tw[0] + tw[1] + tw[2] + tw[3];
    const float rinv = 1.f / s4;

    float4* o0 = reinterpret_cast<float4*>(out + (size_t)t * NE);
    o0[0] = make_float4(w[0], w[1], w[2], w[3]);
    o0[1] = make_float4(w[4], w[5], w[6], w[7]);
    o0[2] = make_float4(w[8], w[9], w[10], w[11]);
    o0[3] = make_float4(w[12], w[13], w[14], w[15]);
    *reinterpret_cast<float4*>(out + TOPW_OFF + (size_t)t * TOPK) =
        make_float4(tw[0] * rinv, tw[1] * rinv, tw[2] * rinv, tw[3] * rinv);
    *reinterpret_cast<float4*>(out + EXP_OFF + (size_t)t * TOPK) =
        make_float4((float)idx[0], (float)idx[1], (float)idx[2], (float)idx[3]);
}

template <int KSL>
static void launch_impl(const float* x, const float* W, float* out, float* ws,
                        hipStream_t stream)
{
    router_partial_kernel<KSL><<<(TOKENS / T_TILE) * KSL, 256, 0, stream>>>(x, W, ws);
    router_finish_kernel<KSL><<<TOKENS / 128, 128, 0, stream>>>(ws, out);
}

extern "C" void kernel_launch(void* const* d_in, const int* in_sizes, int n_in,
                              void* d_out, int out_size, void* d_ws, size_t ws_size,
                              hipStream_t stream) {
    const float* x = (const float*)d_in[0];
    const float* W = (const float*)d_in[1];
    float* out = (float*)d_out;
    float* ws  = (float*)d_ws;

    const size_t per_slice = (size_t)TOKENS * NE * sizeof(float);  // 1 MB
    if (ws_size >= 4 * per_slice) {
        launch_impl<4>(x, W, out, ws, stream);   // 1024 blocks, 4/CU, 16 waves/CU
    } else if (ws_size >= 2 * per_slice) {
        launch_impl<2>(x, W, out, ws, stream);
    } else {
        launch_impl<1>(x, W, out, ws, stream);
    }
}